// Round 1
// baseline (294.870 us; speedup 1.0000x reference)
//
#include <hip/hip_runtime.h>

// NeighbourCovariance: per vertex v, gather K=40 neighbors, weight features by
// exp(-10*distsq), compute per-feature weighted mean (C=3) and covariance (3x3).
// Output layout per vertex: [cov (F*9)] ++ [means (F*3)] = 384 floats.

constexpr int K = 40;
constexpr int C = 3;
constexpr int F = 32;
constexpr float EPS = 1e-3f;
constexpr float DIST_SCALE = 10.0f;
constexpr int OUT_PER_V = F * C * C + F * C; // 384

// 256 threads = 8 vertices/block, 32 lanes (one per feature) per vertex.
__global__ __launch_bounds__(256) void neighcov_kernel(
    const float* __restrict__ coords,    // V x 3
    const float* __restrict__ distsq,    // V x K
    const float* __restrict__ features,  // V x F
    const int*   __restrict__ nidx,      // V x K
    float* __restrict__ out,             // V x 384
    int V)
{
    const int f = threadIdx.x & (F - 1);
    const int v = blockIdx.x * 8 + (threadIdx.x >> 5);
    if (v >= V) return;

    const int*   idx_row = nidx   + (size_t)v * K;
    const float* d_row   = distsq + (size_t)v * K;

    float wsum = 0.f;
    float m0 = 0.f, m1 = 0.f, m2 = 0.f;
    float s00 = 0.f, s01 = 0.f, s02 = 0.f, s11 = 0.f, s12 = 0.f, s22 = 0.f;

    #pragma unroll 4
    for (int k = 0; k < K; ++k) {
        const int idx = idx_row[k];          // wave-broadcast load
        const float d = d_row[k];            // wave-broadcast load
        const bool valid = (idx >= 0);
        const int j = valid ? idx : 0;
        const float w = __expf(-DIST_SCALE * d);
        const float feat = features[(size_t)j * F + f];  // coalesced gather
        const float fw = valid ? feat * w : 0.f;
        const float x = coords[(size_t)j * 3 + 0];       // broadcast
        const float y = coords[(size_t)j * 3 + 1];
        const float z = coords[(size_t)j * 3 + 2];
        wsum += fw;
        m0 += fw * x;  m1 += fw * y;  m2 += fw * z;
        s00 += fw * x * x;  s01 += fw * x * y;  s02 += fw * x * z;
        s11 += fw * y * y;  s12 += fw * y * z;  s22 += fw * z * z;
    }

    const float inv = 1.f / (wsum + EPS);
    const float mu0 = m0 * inv, mu1 = m1 * inv, mu2 = m2 * inv;
    const float c00 = s00 * inv - mu0 * mu0;
    const float c01 = s01 * inv - mu0 * mu1;
    const float c02 = s02 * inv - mu0 * mu2;
    const float c11 = s11 * inv - mu1 * mu1;
    const float c12 = s12 * inv - mu1 * mu2;
    const float c22 = s22 * inv - mu2 * mu2;

    float* o = out + (size_t)v * OUT_PER_V + f * 9;
    o[0] = c00; o[1] = c01; o[2] = c02;
    o[3] = c01; o[4] = c11; o[5] = c12;
    o[6] = c02; o[7] = c12; o[8] = c22;

    float* om = out + (size_t)v * OUT_PER_V + F * 9 + f * 3;
    om[0] = mu0; om[1] = mu1; om[2] = mu2;
}

extern "C" void kernel_launch(void* const* d_in, const int* in_sizes, int n_in,
                              void* d_out, int out_size, void* d_ws, size_t ws_size,
                              hipStream_t stream) {
    const float* coords   = (const float*)d_in[0];
    const float* distsq   = (const float*)d_in[1];
    const float* features = (const float*)d_in[2];
    const int*   nidx     = (const int*)d_in[3];
    float* out = (float*)d_out;

    const int V = in_sizes[0] / C;  // coordinates is V x 3
    const int blocks = (V + 7) / 8; // 8 vertices per 256-thread block

    neighcov_kernel<<<blocks, 256, 0, stream>>>(coords, distsq, features, nidx, out, V);
}

// Round 2
// 254.612 us; speedup vs baseline: 1.1581x; 1.1581x over previous
//
#include <hip/hip_runtime.h>

// NeighbourCovariance: per vertex v, gather K=40 neighbors, weight features by
// exp(-10*distsq), compute per-feature weighted mean (C=3) and covariance (3x3).
// Output layout per vertex: [cov (F*9)] ++ [means (F*3)] = 384 floats.
//
// R2 structure: two-phase.
//  Phase 1: block-cooperative. 320 (v,k) pairs per block; coalesced nidx/distsq
//           loads, ONE exp per pair (was 32x redundant), coord gather with
//           320-way MLP, stage (w,x,y,z) + feature offset in LDS. Invalid
//           neighbors stored as w=0 (no branch needed in phase 2).
//  Phase 2: lane = (vertex, feature). Inner loop: broadcast LDS read + one
//           coalesced 128B feature-row gather + 13 VALU. No load->load chase.

constexpr int K = 40;
constexpr int C = 3;
constexpr int F = 32;
constexpr float EPS = 1e-3f;
constexpr float DIST_SCALE = 10.0f;
constexpr int OUT_PER_V = F * C * C + F * C; // 384
constexpr int VPB = 8;                        // vertices per 256-thread block
constexpr int PAIRS = VPB * K;                // 320

__global__ __launch_bounds__(256) void neighcov_kernel(
    const float* __restrict__ coords,    // V x 3
    const float* __restrict__ distsq,    // V x K
    const float* __restrict__ features,  // V x F
    const int*   __restrict__ nidx,      // V x K
    float* __restrict__ out,             // V x 384
    int V)
{
    __shared__ float4 s_wxyz[PAIRS];  // (w, x, y, z) per (v,k)
    __shared__ int    s_joff[PAIRS];  // j*F element offset into features

    const int tid   = threadIdx.x;
    const int vbase = blockIdx.x * VPB;
    const long long total_pairs = (long long)V * K;

    // ---- Phase 1: stage weights/coords, 320 pairs, high MLP ----
    #pragma unroll
    for (int p = tid; p < PAIRS; p += 256) {
        const long long gp = (long long)vbase * K + p;
        int idx = -1;
        float d = 0.f;
        if (gp < total_pairs) {
            idx = nidx[gp];     // coalesced
            d   = distsq[gp];   // coalesced
        }
        const bool valid = (idx >= 0);
        const int j = valid ? idx : 0;
        const float w = valid ? __expf(-DIST_SCALE * d) : 0.f;
        const float x = coords[(size_t)j * 3 + 0];
        const float y = coords[(size_t)j * 3 + 1];
        const float z = coords[(size_t)j * 3 + 2];
        s_wxyz[p] = make_float4(w, x, y, z);
        s_joff[p] = j * F;
    }
    __syncthreads();

    // ---- Phase 2: one lane per (vertex, feature) ----
    const int f    = tid & (F - 1);
    const int vloc = tid >> 5;
    const int v    = vbase + vloc;
    if (v >= V) return;

    const float4* wp = &s_wxyz[vloc * K];
    const int*    jp = &s_joff[vloc * K];

    float wsum = 0.f;
    float m0 = 0.f, m1 = 0.f, m2 = 0.f;
    float s00 = 0.f, s01 = 0.f, s02 = 0.f, s11 = 0.f, s12 = 0.f, s22 = 0.f;

    #pragma unroll 8
    for (int k = 0; k < K; ++k) {
        const float4 q = wp[k];            // broadcast LDS read (no conflict)
        const int jo   = jp[k];            // broadcast LDS read
        const float feat = features[jo + f];  // coalesced 128B row gather
        const float fw = q.x * feat;       // w==0 encodes invalid neighbor
        const float x = q.y, y = q.z, z = q.w;
        const float fx = fw * x, fy = fw * y, fz = fw * z;
        wsum += fw;
        m0 += fx;        m1 += fy;        m2 += fz;
        s00 += fx * x;   s01 += fx * y;   s02 += fx * z;
        s11 += fy * y;   s12 += fy * z;   s22 += fz * z;
    }

    const float inv = 1.f / (wsum + EPS);
    const float mu0 = m0 * inv, mu1 = m1 * inv, mu2 = m2 * inv;
    const float c00 = s00 * inv - mu0 * mu0;
    const float c01 = s01 * inv - mu0 * mu1;
    const float c02 = s02 * inv - mu0 * mu2;
    const float c11 = s11 * inv - mu1 * mu1;
    const float c12 = s12 * inv - mu1 * mu2;
    const float c22 = s22 * inv - mu2 * mu2;

    float* o = out + (size_t)v * OUT_PER_V + f * 9;
    o[0] = c00; o[1] = c01; o[2] = c02;
    o[3] = c01; o[4] = c11; o[5] = c12;
    o[6] = c02; o[7] = c12; o[8] = c22;

    float* om = out + (size_t)v * OUT_PER_V + F * 9 + f * 3;
    om[0] = mu0; om[1] = mu1; om[2] = mu2;
}

extern "C" void kernel_launch(void* const* d_in, const int* in_sizes, int n_in,
                              void* d_out, int out_size, void* d_ws, size_t ws_size,
                              hipStream_t stream) {
    const float* coords   = (const float*)d_in[0];
    const float* distsq   = (const float*)d_in[1];
    const float* features = (const float*)d_in[2];
    const int*   nidx     = (const int*)d_in[3];
    float* out = (float*)d_out;

    const int V = in_sizes[0] / C;            // coordinates is V x 3
    const int blocks = (V + VPB - 1) / VPB;   // 8 vertices per 256-thread block

    neighcov_kernel<<<blocks, 256, 0, stream>>>(coords, distsq, features, nidx, out, V);
}